// Round 4
// baseline (403.991 us; speedup 1.0000x reference)
//
#include <hip/hip_runtime.h>
#include <hip/hip_cooperative_groups.h>

namespace cg = cooperative_groups;

// ---------------- problem constants ----------------
#define NQ        300
#define NC        80
#define NE        24000      // NQ*NC
#define CAND      1000
#define KSEL      100
#define NPAIRS    4000000
#define HB        4096       // score histogram buckets (float bits >> 18)
#define FHW       65536      // 256*256
#define NMS_THR_F 0.65f
#define MAPS_INIT 0x39E3BFFFu   // order-preserving encode of -1e4f
#define SLOT_CAP  32768      // per-slot record capacity (expected ~13.4K)

#define NBLK      256        // cooperative grid: 1 block/CU, guaranteed co-resident
#define NTHR      1024

typedef unsigned long long ull;

// order-preserving float->u32 encode (monotone: larger float => larger uint)
__device__ __forceinline__ unsigned enc_f32(float f) {
    unsigned u = __float_as_uint(f);
    return (u & 0x80000000u) ? ~u : (u | 0x80000000u);
}
__device__ __forceinline__ float dec_f32(unsigned k) {
    unsigned u = (k & 0x80000000u) ? (k ^ 0x80000000u) : ~k;
    return __uint_as_float(u);
}

// ---------------- single fused cooperative kernel ----------------
// phase 0: zero scratch                      (all blocks)
// phase 1: keys + global score hist + probe  (all blocks)
// phase 2: threshold + compact + sort + emit (block 0)
// phase 3: per-label greedy NMS              (blocks 0..79, wave 0 each)
// phase 4: pick first-100, query->slot       (block 0, wave 0)
// phase 5: stage pairs into per-slot bins    (all blocks, 4 rounds)
// phase 6: per-(sel,band) LDS max + sigmoid  (all blocks, 3-4 tiles each)
__global__ __launch_bounds__(1024, 4) void k_fused(
    const float*    __restrict__ cls,         // [300,81]
    const float*    __restrict__ pboxes,      // [300,4]
    const float4*   __restrict__ seg4,
    const float4*   __restrict__ xy4,
    const int4*     __restrict__ qry4,
    const unsigned* __restrict__ refined_raw,
    ull*            __restrict__ bins,
    unsigned*       __restrict__ slot_tail,
    float4*         __restrict__ cboxes,
    float*          __restrict__ cscore,
    int*            __restrict__ cfeat,
    int*            __restrict__ clabel,
    int*            __restrict__ keepflag,
    float*          __restrict__ sel_score,
    int*            __restrict__ sel_slot,
    int*            __restrict__ qry2slot,
    unsigned*       __restrict__ mode_g,
    ull*            __restrict__ keys,
    unsigned*       __restrict__ hist_g,
    float4*         __restrict__ out4)
{
    cg::grid_group grid = cg::this_grid();
    __shared__ ull      sbuf[4096];            // 32 KB, phase-multiplexed
    __shared__ unsigned small2[512];           // 2 KB: subhist / nms list / stage hist
    __shared__ int      svars[8];
    const int tid = threadIdx.x, b = blockIdx.x;
    const int gid = b * NTHR + tid;

    // ---- phase 0: zero global scratch (ws arrives poisoned) ----
    if (gid < HB)   hist_g[gid] = 0u;
    if (gid < CAND) keepflag[gid] = 0;
    if (gid < KSEL) slot_tail[gid] = 0u;
    if (gid == 0)   *mode_g = 0u;
    grid.sync();

    // ---- phase 1: sigmoid keys + global histogram + refined-layout probe ----
    if (gid < NE) {
        int q = gid / NC, c = gid - q * NC;
        float x = cls[q * (NC + 1) + c];
        float s = 1.f / (1.f + expf(-x));      // scores in (0,1) -> bits monotone
        unsigned bits = __float_as_uint(s);
        keys[gid] = ((ull)bits << 32) | (unsigned)(0xFFFFFFFFu - (unsigned)gid);
        atomicAdd(&hist_g[bits >> 18], 1u);
    }
    // int32 words are strictly 0/1; packed bool bytes are not
    if (gid < 4096 && refined_raw[gid] > 1u) atomicOr(mode_g, 1u);
    grid.sync();

    // ---- phase 2: block 0: 2-level threshold, compact, bitonic sort, emit ----
    if (b == 0) {
        unsigned* hist = (unsigned*)sbuf;              // 16 KB
        for (int i = tid; i < HB; i += NTHR) hist[i] = hist_g[i];
        if (tid < 64) small2[tid] = 0u;                // subhist
        __syncthreads();
        if (tid == 0) {
            int acc = 0, B = 0;
            for (int h = HB - 1; h >= 0; h--) {        // top buckets ~empty; ~50 iters
                acc += (int)hist[h];
                if (acc >= CAND) { B = h; break; }
            }
            svars[0] = B; svars[2] = acc - (int)hist[B]; svars[3] = 0;
        }
        __syncthreads();
        unsigned B = (unsigned)svars[0];

        for (int i = tid; i < NE; i += NTHR) {         // sub-histogram of bucket B
            ull key = keys[i];
            if ((unsigned)(key >> 50) == B)
                atomicAdd(&small2[(unsigned)(key >> 44) & 63u], 1u);
        }
        __syncthreads();
        if (tid == 0) {
            int acc2 = svars[2], T = 0;
            for (int t2 = 63; t2 >= 0; t2--) {
                acc2 += (int)small2[t2];
                if (acc2 >= CAND) { T = t2; break; }
            }
            svars[1] = T; svars[4] = acc2;             // n in [1000, 1000+subbucket]
        }
        __syncthreads();
        unsigned T = (unsigned)svars[1];

        for (int i = tid; i < NE; i += NTHR) {         // compact (clobbers dead hist)
            ull key = keys[i];
            unsigned bkt = (unsigned)(key >> 50);
            unsigned sub = (unsigned)(key >> 44) & 63u;
            if (bkt > B || (bkt == B && sub >= T)) {
                int pos = atomicAdd(&svars[3], 1);
                if (pos < 4096) sbuf[pos] = key;
            }
        }
        __syncthreads();
        int n = min(svars[4], 4096);

        if (n <= 1024) {
            // fast path: one key per thread, descending bitonic, shfl for j<64
            ull r = (tid < n) ? sbuf[tid] : 0ULL;
            for (int k = 2; k <= 1024; k <<= 1) {
                for (int j = k >> 1; j > 0; j >>= 1) {
                    ull p;
                    if (j >= 64) {
                        sbuf[tid] = r; __syncthreads();
                        p = sbuf[tid ^ j]; __syncthreads();
                    } else {
                        p = __shfl_xor(r, j, 64);
                    }
                    bool d = (tid & k) != 0, lower = (tid & j) == 0;
                    r = (d != lower) ? (r > p ? r : p) : (r < p ? r : p);
                }
            }
            sbuf[tid] = r;
            __syncthreads();
        } else {
            // fallback: generic LDS bitonic over next pow2
            int nsort = 2048; while (nsort < n) nsort <<= 1;
            for (int i = n + tid; i < nsort; i += NTHR) sbuf[i] = 0ULL;
            __syncthreads();
            for (int k = 2; k <= nsort; k <<= 1) {
                for (int j = k >> 1; j > 0; j >>= 1) {
                    for (int i = tid; i < nsort; i += NTHR) {
                        int ixj = i ^ j;
                        if (ixj > i) {
                            ull a = sbuf[i], c = sbuf[ixj];
                            bool up = ((i & k) == 0);
                            if (up ? (a < c) : (a > c)) { sbuf[i] = c; sbuf[ixj] = a; }
                        }
                    }
                    __syncthreads();
                }
            }
        }

        if (tid < CAND) {
            ull key = sbuf[tid];
            unsigned bits = (unsigned)(key >> 32);
            unsigned e = 0xFFFFFFFFu - (unsigned)(key & 0xFFFFFFFFu);
            int feat = (int)e / NC, lab = (int)e - feat * NC;
            cscore[tid] = __uint_as_float(bits);
            cfeat[tid]  = feat;
            clabel[tid] = lab;
            float off = 4.f * (float)lab;              // class-aware box offset
            float4 bb;
            bb.x = pboxes[feat * 4 + 0] + off; bb.y = pboxes[feat * 4 + 1] + off;
            bb.z = pboxes[feat * 4 + 2] + off; bb.w = pboxes[feat * 4 + 3] + off;
            cboxes[tid] = bb;
        }
    }
    grid.sync();

    // ---- phase 3: NMS, label = blockIdx, wave 0 only (wave-synchronous LDS) ----
    if (b < NC && tid < 64) {
        int lab = b, lane = tid;
        int* list = (int*)small2;                      // 256 ints
        int base = 0;
        for (int c = 0; c < CAND; c += 64) {           // ordered compaction of label
            int i = c + lane;
            bool m = (i < CAND) && (clabel[i] == lab);
            ull bal = __ballot(m);
            int rank = __popcll(bal & ((1ULL << lane) - 1ULL));
            if (m && base + rank < 256) list[base + rank] = i;
            base += __popcll(bal);
        }
        int n = min(base, 256);

        float4 bx[4]; float area[4];
        unsigned keepm = 0;
        #pragma unroll
        for (int s = 0; s < 4; s++) {
            int j = (s << 6) + lane;
            if (j < n) {
                bx[s] = cboxes[list[j]];
                area[s] = (bx[s].z - bx[s].x) * (bx[s].w - bx[s].y);
                keepm |= (1u << s);
            }
        }
        #pragma unroll
        for (int slot = 0; slot < 4; slot++) {         // sequential greedy
            int i0 = slot << 6;
            if (i0 >= n) break;
            int iend = min(64, n - i0);
            for (int l = 0; l < iend; l++) {
                int i = i0 + l;
                unsigned km = __shfl(keepm, l);
                bool keep_i = (km >> slot) & 1u;       // uniform
                float bix = __shfl(bx[slot].x, l), biy = __shfl(bx[slot].y, l);
                float biz = __shfl(bx[slot].z, l), biw = __shfl(bx[slot].w, l);
                float ai  = __shfl(area[slot], l);
                if (keep_i) {
                    #pragma unroll
                    for (int s2 = 0; s2 < 4; s2++) {
                        int j = (s2 << 6) + lane;
                        if (j > i && j < n && ((keepm >> s2) & 1u)) {
                            float xx1 = fmaxf(bix, bx[s2].x), yy1 = fmaxf(biy, bx[s2].y);
                            float xx2 = fminf(biz, bx[s2].z), yy2 = fminf(biw, bx[s2].w);
                            float inter = fmaxf(xx2 - xx1, 0.f) * fmaxf(yy2 - yy1, 0.f);
                            float uni = ai + area[s2] - inter;
                            if (inter / fmaxf(uni, 1e-9f) > NMS_THR_F) keepm &= ~(1u << s2);
                        }
                    }
                }
            }
        }
        #pragma unroll
        for (int s = 0; s < 4; s++) {
            int j = (s << 6) + lane;
            if (j < n) keepflag[list[j]] = (keepm >> s) & 1u;
        }
    }
    grid.sync();

    // ---- phase 4: pick first-100 kept, build query->slot (block 0, wave 0) ----
    if (b == 0 && tid < 64) {
        int lane = tid;
        float* ss  = (float*)sbuf;                     // [100]
        int*   sf  = (int*)sbuf + 128;                 // [100]
        int*   q2s = (int*)sbuf + 256;                 // [300]
        int base = 0;
        for (int c = 0; c < CAND; c += 64) {
            int i = c + lane;
            bool k = (i < CAND) && (keepflag[i] != 0);
            ull bal = __ballot(k);
            int rank = __popcll(bal & ((1ULL << lane) - 1ULL));
            int pos = base + rank;
            if (k && pos < KSEL) { ss[pos] = cscore[i]; sf[pos] = cfeat[i]; }
            base += __popcll(bal);
        }
        for (int q = lane; q < NQ; q += 64) q2s[q] = -1;
        if (lane == 0) {
            int nsel = min(base, KSEL), nslots = 0;
            for (int s = 0; s < KSEL; s++) {
                if (s < nsel) {
                    int f = sf[s];
                    int sl = q2s[f];
                    if (sl < 0) { sl = nslots++; q2s[f] = sl; }
                    sel_slot[s] = sl; sel_score[s] = ss[s];
                } else {
                    sel_slot[s] = -1; sel_score[s] = 0.f;  // pads -> exact 0 rows
                }
            }
        }
        for (int q = lane; q < NQ; q += 64) qry2slot[q] = q2s[q];
    }
    grid.sync();

    // ---- phase 5: stage active pairs into per-slot bins (4 rounds) ----
    {
        unsigned* hist100 = small2;                    // [0..99]
        unsigned* gbase   = small2 + 128;              // [128..227]
        unsigned mode = *mode_g;
        for (int it = 0; it < 4; it++) {
            if (tid < KSEL) hist100[tid] = 0u;
            __syncthreads();
            int t = it * (NBLK * NTHR) + gid;          // 4-pair group index
            unsigned addr[4], encw[4], rnk[4]; int nloc = 0;
            if (t < (NPAIRS / 4)) {
                int4 q = qry4[t];
                int s0 = qry2slot[q.x], s1 = qry2slot[q.y];
                int s2 = qry2slot[q.z], s3 = qry2slot[q.w];
                if ((s0 & s1 & s2 & s3) >= 0) {        // sign-AND: false only if all -1
                    float4 sg   = seg4[t];
                    float4 xy01 = xy4[2 * t], xy23 = xy4[2 * t + 1];
                    unsigned r0, r1, r2, r3;
                    if (mode) {                        // packed bool bytes
                        unsigned rb = refined_raw[t];
                        r0 = rb & 255u; r1 = (rb >> 8) & 255u;
                        r2 = (rb >> 16) & 255u; r3 = rb >> 24;
                    } else {                           // int32 words
                        uint4 rr = ((const uint4*)refined_raw)[t];
                        r0 = rr.x; r1 = rr.y; r2 = rr.z; r3 = rr.w;
                    }
                    #define MK_REC(S, PX, PY, W, R)                                       \
                        if (S >= 0) {                                                     \
                            int px = min(max((int)((PX) * 256.f), 0), 255);               \
                            int py = min(max((int)((PY) * 256.f), 0), 255);               \
                            float w = (R) ? 2.f * (W) : (W);                              \
                            addr[nloc] = ((unsigned)S << 16) | ((unsigned)py << 8) | (unsigned)px; \
                            encw[nloc] = enc_f32(w);                                      \
                            rnk[nloc]  = atomicAdd(&hist100[S], 1u);                      \
                            nloc++;                                                       \
                        }
                    MK_REC(s0, xy01.x, xy01.y, sg.x, r0)
                    MK_REC(s1, xy01.z, xy01.w, sg.y, r1)
                    MK_REC(s2, xy23.x, xy23.y, sg.z, r2)
                    MK_REC(s3, xy23.z, xy23.w, sg.w, r3)
                    #undef MK_REC
                }
            }
            __syncthreads();
            if (tid < KSEL && hist100[tid] > 0u)
                gbase[tid] = atomicAdd(&slot_tail[tid], hist100[tid]);
            __syncthreads();
            for (int k2 = 0; k2 < nloc; k2++) {
                unsigned s = addr[k2] >> 16;
                unsigned pos = gbase[s] + rnk[k2];
                if (pos < SLOT_CAP)
                    bins[(size_t)s * SLOT_CAP + pos] = ((ull)encw[k2] << 32) | addr[k2];
            }
            // next iter's hist zero touches [0..99]; gbase [128..227] re-written
            // only after two barriers -> no extra barrier needed here
        }
    }
    grid.sync();

    // ---- phase 6: per (selection, 32-row band): LDS max + fused sigmoid out ----
    for (int tile = b; tile < KSEL * 8; tile += NBLK) {
        int i = tile >> 3, h = tile & 7;
        int slot = sel_slot[i];
        float sc = sel_score[i];
        long obase = (long)i * (FHW / 4) + h * 2048;   // float4 index

        if (slot < 0) {                                // pad selection -> zero rows
            float4 z = {0.f, 0.f, 0.f, 0.f};
            out4[obase + tid] = z;
            out4[obase + 1024 + tid] = z;
        } else {
            unsigned* tl = (unsigned*)sbuf;            // 32 rows x 256 cols
            __syncthreads();                           // prior tile's reads complete
            #pragma unroll
            for (int k2 = 0; k2 < 8; k2++) tl[tid + (k2 << 10)] = MAPS_INIT;
            __syncthreads();
            unsigned tot = min(slot_tail[slot], (unsigned)SLOT_CAP);
            const ull* segp = bins + (size_t)slot * SLOT_CAP;
            for (unsigned j = tid; j < tot; j += NTHR) {
                ull r = segp[j];
                unsigned a = (unsigned)r;
                if (((a >> 13) & 7u) == (unsigned)h)   // py>>5 == h
                    atomicMax(&tl[a & 8191u], (unsigned)(r >> 32));
            }
            __syncthreads();
            #pragma unroll
            for (int k2 = 0; k2 < 2; k2++) {
                int j = tid + (k2 << 10);              // float4 index within band
                unsigned m0 = tl[4 * j + 0], m1 = tl[4 * j + 1];
                unsigned m2 = tl[4 * j + 2], m3 = tl[4 * j + 3];
                float4 v;
                v.x = sc / (1.f + expf(-dec_f32(m0))); // m=-1e4 -> exp=inf -> exact 0
                v.y = sc / (1.f + expf(-dec_f32(m1)));
                v.z = sc / (1.f + expf(-dec_f32(m2)));
                v.w = sc / (1.f + expf(-dec_f32(m3)));
                out4[obase + j] = v;
            }
        }
    }
}

// ---------------- launch ----------------
extern "C" void kernel_launch(void* const* d_in, const int* in_sizes, int n_in,
                              void* d_out, int out_size, void* d_ws, size_t ws_size,
                              hipStream_t stream) {
    const float*    cls     = (const float*)d_in[0];
    const float*    pboxes  = (const float*)d_in[1];
    const float4*   seg4    = (const float4*)d_in[2];
    const float4*   xy4     = (const float4*)d_in[3];
    const int4*     qry4    = (const int4*)d_in[4];
    const unsigned* refined = (const unsigned*)d_in[5];
    // d_in[6] map_ids: unused by the reference
    float4* out4 = (float4*)d_out;

    char* ws = (char*)d_ws;
    ull*       bins      = (ull*)ws;                            // 100*32768*8 = 26,214,400 B
    unsigned*  slot_tail = (unsigned*)(ws + 26214400);          // 400 B
    float4*    cboxes    = (float4*)  (ws + 26214800);          // 16,000 B (16-aligned)
    float*     cscore    = (float*)   (ws + 26230800);          // 4,000 B
    int*       cfeat     = (int*)     (ws + 26234800);          // 4,000 B
    int*       clabel    = (int*)     (ws + 26238800);          // 4,000 B
    int*       keepflag  = (int*)     (ws + 26242800);          // 4,000 B
    float*     sel_score = (float*)   (ws + 26246800);          // 400 B
    int*       sel_slot  = (int*)     (ws + 26247200);          // 400 B
    int*       qry2slot  = (int*)     (ws + 26247600);          // 1,200 B
    unsigned*  mode_g    = (unsigned*)(ws + 26248800);          // 4 B (+4 pad)
    ull*       keys      = (ull*)     (ws + 26248808);          // 24000*8 = 192,000 B
    unsigned*  hist_g    = (unsigned*)(ws + 26440808);          // 4096*4 = 16,384 B

    void* args[] = {
        (void*)&cls, (void*)&pboxes, (void*)&seg4, (void*)&xy4, (void*)&qry4,
        (void*)&refined, (void*)&bins, (void*)&slot_tail, (void*)&cboxes,
        (void*)&cscore, (void*)&cfeat, (void*)&clabel, (void*)&keepflag,
        (void*)&sel_score, (void*)&sel_slot, (void*)&qry2slot, (void*)&mode_g,
        (void*)&keys, (void*)&hist_g, (void*)&out4
    };
    hipLaunchCooperativeKernel((void*)k_fused, dim3(NBLK), dim3(NTHR),
                               args, 0, stream);
}

// Round 5
// 222.477 us; speedup vs baseline: 1.8159x; 1.8159x over previous
//
#include <hip/hip_runtime.h>

// ---------------- problem constants ----------------
#define NQ        300
#define NC        80
#define NE        24000      // NQ*NC
#define CAND      1000
#define KSEL      100
#define NPAIRS    4000000
#define HB        4096       // score histogram buckets (float bits >> 18)
#define FHW       65536      // 256*256
#define NMS_THR_F 0.65f
#define MAPS_INIT 0x39E3BFFFu   // order-preserving encode of -1e4f

#define NBLK_A    977        // stage blocks: 977*1024*4 pairs >= 4M
#define NBIN      800        // (slot,band) bins: 100 slots x 8 bands
#define BAND_CAP  8192       // per-bin record capacity (expected ~1.7K; huge headroom)

typedef unsigned long long ull;

// order-preserving float->u32 encode (monotone: larger float => larger uint)
__device__ __forceinline__ unsigned enc_f32(float f) {
    unsigned u = __float_as_uint(f);
    return (u & 0x80000000u) ? ~u : (u | 0x80000000u);
}
__device__ __forceinline__ float dec_f32(unsigned k) {
    unsigned u = (k & 0x80000000u) ? (k ^ 0x80000000u) : ~k;
    return __uint_as_float(u);
}

// ---------------- K1: sigmoid scores -> top-1000 sorted candidates ----------------
// also: zero bin tails / keepflag, probe refined_mask layout (parallel, free here)
__global__ __launch_bounds__(1024) void k_select(
    const float* __restrict__ cls,        // [300,81]
    const float* __restrict__ pboxes,     // [300,4]
    float4* __restrict__ cboxes, float* __restrict__ cscore,
    int* __restrict__ cfeat, int* __restrict__ clabel,
    unsigned* __restrict__ bin_tail, int* __restrict__ keepflag,
    const unsigned* __restrict__ refined_raw, unsigned* __restrict__ mode_flag)
{
    __shared__ ull sbuf[4096];                         // 32 KB, aliases hist
    unsigned* hist = (unsigned*)sbuf;                  // first 16 KB
    __shared__ unsigned subhist[64];
    __shared__ int sB, sT, sAbove, sCount, sN;
    __shared__ unsigned smode;
    int tid = threadIdx.x;

    if (tid < NBIN) bin_tail[tid] = 0u;                // reset per-(slot,band) tails
    if (tid < CAND) keepflag[tid] = 0;
    if (tid == 0) smode = 0u;

    for (int b = tid; b < HB; b += 1024) hist[b] = 0u;
    if (tid < 64) subhist[tid] = 0u;
    __syncthreads();

    // probe refined_mask layout: int32 words are strictly 0/1; packed bool bytes are not
    {
        unsigned any = 0;
        for (int i = tid; i < 4096; i += 1024) if (refined_raw[i] > 1u) any = 1;
        if (any) atomicOr(&smode, 1u);
    }

    ull lk[24];
    #pragma unroll
    for (int k = 0; k < 24; k++) {
        int e = tid + (k << 10);
        if (e < NE) {
            int q = e / NC, c = e - q * NC;
            float x = cls[q * (NC + 1) + c];
            float s = 1.f / (1.f + expf(-x));          // scores in (0,1) -> bits monotone
            unsigned bits = __float_as_uint(s);
            lk[k] = ((ull)bits << 32) | (unsigned)(0xFFFFFFFFu - (unsigned)e);
            atomicAdd(&hist[bits >> 18], 1u);
        }
    }
    __syncthreads();

    if (tid == 0) {
        int acc = 0, B = 0;
        for (int b = HB - 1; b >= 0; b--) {            // top buckets ~empty; ~50 iters
            acc += (int)hist[b];
            if (acc >= CAND) { B = b; break; }
        }
        sB = B; sAbove = acc - (int)hist[B]; sCount = 0;
        *mode_flag = smode;
    }
    __syncthreads();
    unsigned B = (unsigned)sB;

    #pragma unroll
    for (int k = 0; k < 24; k++) {                     // sub-histogram of bucket B
        int e = tid + (k << 10);
        if (e < NE && (unsigned)(lk[k] >> 50) == B)
            atomicAdd(&subhist[(unsigned)(lk[k] >> 44) & 63u], 1u);
    }
    __syncthreads();
    if (tid == 0) {
        int acc2 = sAbove, T = 0;
        for (int t = 63; t >= 0; t--) {
            acc2 += (int)subhist[t];
            if (acc2 >= CAND) { T = t; break; }
        }
        sT = T; sN = acc2;                             // n in [1000, 1000+subbucket]
    }
    __syncthreads();
    unsigned T = (unsigned)sT;

    #pragma unroll
    for (int k = 0; k < 24; k++) {                     // compact qualifying keys
        int e = tid + (k << 10);
        if (e < NE) {
            ull key = lk[k];
            unsigned bkt = (unsigned)(key >> 50);
            unsigned sub = (unsigned)(key >> 44) & 63u;
            if (bkt > B || (bkt == B && sub >= T)) {
                int pos = atomicAdd(&sCount, 1);
                if (pos < 4096) sbuf[pos] = key;
            }
        }
    }
    __syncthreads();
    int n = min(sN, 4096);

    if (n <= 1024) {
        // fast path: one key per thread, descending bitonic, shfl for j<64
        ull r = (tid < n) ? sbuf[tid] : 0ULL;
        for (int k = 2; k <= 1024; k <<= 1) {
            for (int j = k >> 1; j > 0; j >>= 1) {
                ull p;
                if (j >= 64) {
                    sbuf[tid] = r; __syncthreads();
                    p = sbuf[tid ^ j]; __syncthreads();
                } else {
                    p = __shfl_xor(r, j, 64);
                }
                bool d = (tid & k) != 0, lower = (tid & j) == 0;
                r = (d != lower) ? (r > p ? r : p) : (r < p ? r : p);
            }
        }
        sbuf[tid] = r;
        __syncthreads();
    } else {
        // fallback: generic LDS bitonic over next pow2
        int nsort = 2048; while (nsort < n) nsort <<= 1;
        for (int i = n + tid; i < nsort; i += 1024) sbuf[i] = 0ULL;
        __syncthreads();
        for (int k = 2; k <= nsort; k <<= 1) {
            for (int j = k >> 1; j > 0; j >>= 1) {
                for (int i = tid; i < nsort; i += 1024) {
                    int ixj = i ^ j;
                    if (ixj > i) {
                        ull a = sbuf[i], b = sbuf[ixj];
                        bool up = ((i & k) == 0);
                        if (up ? (a < b) : (a > b)) { sbuf[i] = b; sbuf[ixj] = a; }
                    }
                }
                __syncthreads();
            }
        }
    }

    if (tid < CAND) {
        ull key = sbuf[tid];
        unsigned bits = (unsigned)(key >> 32);
        unsigned e = 0xFFFFFFFFu - (unsigned)(key & 0xFFFFFFFFu);
        int feat = (int)e / NC, lab = (int)e - feat * NC;
        cscore[tid] = __uint_as_float(bits);
        cfeat[tid]  = feat;
        clabel[tid] = lab;
        float off = 4.f * (float)lab;                  // class-aware box offset
        float4 b;
        b.x = pboxes[feat * 4 + 0] + off; b.y = pboxes[feat * 4 + 1] + off;
        b.z = pboxes[feat * 4 + 2] + off; b.w = pboxes[feat * 4 + 3] + off;
        cboxes[tid] = b;
    }
}

// ---------------- K2: per-label greedy NMS, one wave per label (parallel) --------
__global__ __launch_bounds__(64) void k_nms(
    const float4* __restrict__ cboxes, const int* __restrict__ clabel,
    int* __restrict__ keepflag)
{
    int lab = blockIdx.x, lane = threadIdx.x;
    __shared__ int list[256];
    int base = 0;
    for (int c = 0; c < CAND; c += 64) {               // ordered compaction of this label
        int i = c + lane;
        bool m = (i < CAND) && (clabel[i] == lab);
        ull bal = __ballot(m);
        int rank = __popcll(bal & ((1ULL << lane) - 1ULL));
        if (m && base + rank < 256) list[base + rank] = i;
        base += __popcll(bal);
    }
    __syncthreads();
    int n = min(base, 256);

    float4 bx[4]; float area[4];
    unsigned keepm = 0;
    #pragma unroll
    for (int s = 0; s < 4; s++) {
        int j = (s << 6) + lane;
        if (j < n) {
            bx[s] = cboxes[list[j]];
            area[s] = (bx[s].z - bx[s].x) * (bx[s].w - bx[s].y);
            keepm |= (1u << s);
        }
    }
    #pragma unroll
    for (int slot = 0; slot < 4; slot++) {             // sequential greedy over this label
        int i0 = slot << 6;
        if (i0 >= n) break;
        int iend = min(64, n - i0);
        for (int l = 0; l < iend; l++) {
            int i = i0 + l;
            unsigned km = __shfl(keepm, l);
            bool keep_i = (km >> slot) & 1u;           // uniform
            float bix = __shfl(bx[slot].x, l), biy = __shfl(bx[slot].y, l);
            float biz = __shfl(bx[slot].z, l), biw = __shfl(bx[slot].w, l);
            float ai  = __shfl(area[slot], l);
            if (keep_i) {
                #pragma unroll
                for (int s2 = 0; s2 < 4; s2++) {
                    int j = (s2 << 6) + lane;
                    if (j > i && j < n && ((keepm >> s2) & 1u)) {
                        float xx1 = fmaxf(bix, bx[s2].x), yy1 = fmaxf(biy, bx[s2].y);
                        float xx2 = fminf(biz, bx[s2].z), yy2 = fminf(biw, bx[s2].w);
                        float inter = fmaxf(xx2 - xx1, 0.f) * fmaxf(yy2 - yy1, 0.f);
                        float uni = ai + area[s2] - inter;
                        if (inter / fmaxf(uni, 1e-9f) > NMS_THR_F) keepm &= ~(1u << s2);
                    }
                }
            }
        }
    }
    #pragma unroll
    for (int s = 0; s < 4; s++) {
        int j = (s << 6) + lane;
        if (j < n) keepflag[list[j]] = (keepm >> s) & 1u;
    }
}

// ---------------- K3: pick first-100 kept, build query->slot table ----------------
__global__ __launch_bounds__(64) void k_pick(
    const float* __restrict__ cscore, const int* __restrict__ cfeat,
    const int* __restrict__ keepflag,
    float* __restrict__ sel_score, int* __restrict__ sel_slot,
    int* __restrict__ qry2slot)
{
    int lane = threadIdx.x;
    __shared__ float ss[KSEL];
    __shared__ int   sf[KSEL];
    __shared__ int   q2s[NQ];

    int base = 0;                                      // first-100 kept, in sorted order
    for (int c = 0; c < CAND; c += 64) {
        int i = c + lane;
        bool k = (i < CAND) && (keepflag[i] != 0);
        ull bal = __ballot(k);
        int rank = __popcll(bal & ((1ULL << lane) - 1ULL));
        int pos = base + rank;
        if (k && pos < KSEL) { ss[pos] = cscore[i]; sf[pos] = cfeat[i]; }
        base += __popcll(bal);
    }
    for (int q = lane; q < NQ; q += 64) q2s[q] = -1;
    __syncthreads();
    if (lane == 0) {
        int nsel = min(base, KSEL), nslots = 0;
        for (int s = 0; s < KSEL; s++) {
            if (s < nsel) {
                int f = sf[s];
                int sl = q2s[f];
                if (sl < 0) { sl = nslots++; q2s[f] = sl; }
                sel_slot[s] = sl; sel_score[s] = ss[s];
            } else {
                sel_slot[s] = -1; sel_score[s] = 0.f;  // -inf pads -> exact 0 rows
            }
        }
    }
    __syncthreads();
    for (int q = lane; q < NQ; q += 64) qry2slot[q] = q2s[q];
}

// ---------------- K4: stage active pairs into per-(slot,band) bins --------------
// record = (encw << 32) | (slot<<16 | py<<8 | px); bin id = addr>>13 (0..799).
// per-block LDS hist(800) -> one global atomicAdd per (block,bin) -> direct write.
// order within a bin is non-deterministic; harmless (max is commutative).
__global__ __launch_bounds__(1024) void k_stage(
    const float4* __restrict__ seg4, const float4* __restrict__ xy4,
    const int4* __restrict__ qry4, const unsigned* __restrict__ refined_raw,
    const int* __restrict__ qry2slot, const unsigned* __restrict__ mode_flag,
    ull* __restrict__ bins, unsigned* __restrict__ bin_tail)
{
    __shared__ unsigned hist[NBIN];
    __shared__ unsigned gbase[NBIN];
    int tid = threadIdx.x, b = blockIdx.x;
    if (tid < NBIN) hist[tid] = 0u;
    __syncthreads();

    int t = b * 1024 + tid;                            // 4-pair group index
    unsigned addr[4], encw[4], rnk[4]; int nloc = 0;
    if (t < (NPAIRS / 4)) {
        int4 q = qry4[t];
        int s0 = qry2slot[q.x], s1 = qry2slot[q.y];
        int s2 = qry2slot[q.z], s3 = qry2slot[q.w];
        if ((s0 & s1 & s2 & s3) >= 0 || s0 >= 0 || s1 >= 0 || s2 >= 0 || s3 >= 0) {
            float4 sg   = seg4[t];
            float4 xy01 = xy4[2 * t], xy23 = xy4[2 * t + 1];
            unsigned r0, r1, r2, r3;
            if (*mode_flag) {                          // packed bool bytes
                unsigned rb = refined_raw[t];
                r0 = rb & 255u; r1 = (rb >> 8) & 255u; r2 = (rb >> 16) & 255u; r3 = rb >> 24;
            } else {                                   // int32 words
                uint4 rr = ((const uint4*)refined_raw)[t];
                r0 = rr.x; r1 = rr.y; r2 = rr.z; r3 = rr.w;
            }
            #define MK_REC(S, PX, PY, W, R)                                       \
                if (S >= 0) {                                                     \
                    int px = min(max((int)((PX) * 256.f), 0), 255);               \
                    int py = min(max((int)((PY) * 256.f), 0), 255);               \
                    float w = (R) ? 2.f * (W) : (W);                              \
                    unsigned a = ((unsigned)S << 16) | ((unsigned)py << 8) | (unsigned)px; \
                    addr[nloc] = a;                                               \
                    encw[nloc] = enc_f32(w);                                      \
                    rnk[nloc]  = atomicAdd(&hist[a >> 13], 1u);                   \
                    nloc++;                                                       \
                }
            MK_REC(s0, xy01.x, xy01.y, sg.x, r0)
            MK_REC(s1, xy01.z, xy01.w, sg.y, r1)
            MK_REC(s2, xy23.x, xy23.y, sg.z, r2)
            MK_REC(s3, xy23.z, xy23.w, sg.w, r3)
            #undef MK_REC
        }
    }
    __syncthreads();
    for (int i = tid; i < NBIN; i += 1024)
        if (hist[i] > 0u) gbase[i] = atomicAdd(&bin_tail[i], hist[i]);
    __syncthreads();

    for (int k = 0; k < nloc; k++) {
        unsigned hb = addr[k] >> 13;
        unsigned pos = gbase[hb] + rnk[k];
        if (pos < BAND_CAP)
            bins[(size_t)hb * BAND_CAP + pos] = ((ull)encw[k] << 32) | addr[k];
    }
}

// ---------------- K5: per (selection, 32-row band): LDS max + fused sigmoid out ----
// 800 blocks: i = blk>>3 (selection), h = blk&7 (band). Reads ONLY its bin.
__global__ __launch_bounds__(1024) void k_tile_out(
    const ull* __restrict__ bins, const unsigned* __restrict__ bin_tail,
    const float* __restrict__ sel_score, const int* __restrict__ sel_slot,
    float4* __restrict__ out4)
{
    __shared__ unsigned tile[8192];                    // 32 rows x 256 cols
    int tid = threadIdx.x;
    int i = blockIdx.x >> 3, h = blockIdx.x & 7;
    int slot = sel_slot[i];
    float sc = sel_score[i];
    long obase = (long)i * (FHW / 4) + h * 2048;       // float4 index

    if (slot < 0) {                                    // pad selection -> exact zero rows
        float4 z = {0.f, 0.f, 0.f, 0.f};
        out4[obase + tid] = z;
        out4[obase + 1024 + tid] = z;
        return;
    }

    #pragma unroll
    for (int k = 0; k < 8; k++) tile[tid + (k << 10)] = MAPS_INIT;
    __syncthreads();

    int hb = slot * 8 + h;
    unsigned tot = min(bin_tail[hb], (unsigned)BAND_CAP);
    const ull* segp = bins + (size_t)hb * BAND_CAP;
    for (unsigned j = tid; j < tot; j += 1024) {
        ull r = segp[j];
        atomicMax(&tile[(unsigned)r & 8191u], (unsigned)(r >> 32));
    }
    __syncthreads();

    #pragma unroll
    for (int k = 0; k < 2; k++) {
        int j = tid + (k << 10);                       // float4 index within band
        unsigned m0 = tile[4 * j + 0], m1 = tile[4 * j + 1];
        unsigned m2 = tile[4 * j + 2], m3 = tile[4 * j + 3];
        float4 v;
        v.x = sc / (1.f + expf(-dec_f32(m0)));         // m=-1e4 -> exp=inf -> exactly 0
        v.y = sc / (1.f + expf(-dec_f32(m1)));
        v.z = sc / (1.f + expf(-dec_f32(m2)));
        v.w = sc / (1.f + expf(-dec_f32(m3)));
        out4[obase + j] = v;
    }
}

// ---------------- launch ----------------
extern "C" void kernel_launch(void* const* d_in, const int* in_sizes, int n_in,
                              void* d_out, int out_size, void* d_ws, size_t ws_size,
                              hipStream_t stream) {
    const float*    cls     = (const float*)d_in[0];
    const float*    pboxes  = (const float*)d_in[1];
    const float4*   seg4    = (const float4*)d_in[2];
    const float4*   xy4     = (const float4*)d_in[3];
    const int4*     qry4    = (const int4*)d_in[4];
    const unsigned* refined = (const unsigned*)d_in[5];
    // d_in[6] map_ids: unused by the reference
    float* out = (float*)d_out;

    char* ws = (char*)d_ws;
    ull*       bins      = (ull*)ws;                            // 800*8192*8 = 52,428,800 B
    unsigned*  bin_tail  = (unsigned*)(ws + 52428800);          // 3,200 B
    float4*    cboxes    = (float4*)  (ws + 52432000);          // 16,000 B (16-aligned)
    float*     cscore    = (float*)   (ws + 52448000);          // 4,000 B
    int*       cfeat     = (int*)     (ws + 52452000);          // 4,000 B
    int*       clabel    = (int*)     (ws + 52456000);          // 4,000 B
    int*       keepflag  = (int*)     (ws + 52460000);          // 4,000 B
    float*     sel_score = (float*)   (ws + 52464000);          // 400 B
    int*       sel_slot  = (int*)     (ws + 52464400);          // 400 B
    int*       qry2slot  = (int*)     (ws + 52464800);          // 1,200 B
    unsigned*  mode_flag = (unsigned*)(ws + 52466000);          // 4 B

    k_select  <<<1, 1024, 0, stream>>>(cls, pboxes, cboxes, cscore, cfeat, clabel,
                                       bin_tail, keepflag, refined, mode_flag);
    k_nms     <<<NC, 64, 0, stream>>>(cboxes, clabel, keepflag);
    k_pick    <<<1, 64, 0, stream>>>(cscore, cfeat, keepflag, sel_score, sel_slot,
                                     qry2slot);
    k_stage   <<<NBLK_A, 1024, 0, stream>>>(seg4, xy4, qry4, refined, qry2slot, mode_flag,
                                            bins, bin_tail);
    k_tile_out<<<KSEL * 8, 1024, 0, stream>>>(bins, bin_tail, sel_score, sel_slot,
                                              (float4*)out);
}